// Round 7
// baseline (232.292 us; speedup 1.0000x reference)
//
#include <hip/hip_runtime.h>

#define E 4096
#define H 32
#define L 8192
#define SCALE 0.08838834764831845f  // 1/sqrt(128)

typedef float fv4 __attribute__((ext_vector_type(4)));

__device__ __forceinline__ fv4 ntload4(const float* p) {
  return __builtin_nontemporal_load(reinterpret_cast<const fv4*>(p));
}
__device__ __forceinline__ void ntstore4(float* p, fv4 v) {
  __builtin_nontemporal_store(v, reinterpret_cast<fv4*>(p));
}

// ---------------- K0: zero the q/k/v accumulator region ---------------------
__global__ __launch_bounds__(256) void zero_ws(float* __restrict__ ws, int n) {
  int i = blockIdx.x * 256 + threadIdx.x;
  if (i < n) ws[i] = 0.f;
}

// ---------------- K1: fused q/k/v GEMV (split-K, 4-rep atomic partials) -----
__global__ __launch_bounds__(256) void gemv_qkv(const float* __restrict__ x,
    const float* __restrict__ Wq, const float* __restrict__ Wk,
    const float* __restrict__ Wv, float* __restrict__ qacc,
    float* __restrict__ kacc, float* __restrict__ vacc) {
  int b = blockIdx.x;            // 384 blocks: 3 mats x 32 chunks x 4 col-groups
  int mat = b >> 7;
  int rem = b & 127;
  int chunk = rem >> 2;          // 32 chunks of 128 rows
  int g = rem & 3;               // 4 col groups of 1024
  const float* W = (mat == 0) ? Wq : (mat == 1) ? Wk : Wv;
  float* accb = (mat == 0) ? qacc : (mat == 1) ? kacc : vacc;
  int rep = (b >> 2) & 3;
  float* acc = accb + (rep << 12);
  int t = threadIdx.x;
  int j = (g << 10) + (t << 2);
  float ax = 0.f, ay = 0.f, az = 0.f, aw = 0.f;
  int i0 = chunk << 7;
  #pragma unroll 8
  for (int r = 0; r < 128; ++r) {
    int i = i0 + r;
    float xi = x[i];
    const fv4 w4 = ntload4(W + (size_t)i * E + j);
    ax += xi * w4.x; ay += xi * w4.y; az += xi * w4.z; aw += xi * w4.w;
  }
  atomicAdd(acc + j + 0, ax);
  atomicAdd(acc + j + 1, ay);
  atomicAdd(acc + j + 2, az);
  atomicAdd(acc + j + 3, aw);
}

// ---------------- K2: fused k+v shift + logits + accumulation ---------------
// PARTIAL=true : per-block exclusive partial stores (no RMW, no contention).
// PARTIAL=false: R6-style 16-replica atomics (fallback for small ws).
__device__ __forceinline__ void load_slot(int o, int t,
    const float* __restrict__ kin, const float* __restrict__ vin,
    const float* __restrict__ kacc, const float* __restrict__ vacc,
    const float* __restrict__ bk, const float* __restrict__ bv,
    fv4 k4[4], fv4 v4[4]) {
  if (o < L - 1) {
    const float* ks = kin + (size_t)(o + 1) * E;
    const float* vs = vin + (size_t)(o + 1) * E;
    #pragma unroll
    for (int c = 0; c < 4; ++c) {
      int e = (c << 10) + (t << 2);
      k4[c] = ntload4(ks + e);
      v4[c] = ntload4(vs + e);
    }
  } else {
    #pragma unroll
    for (int c = 0; c < 4; ++c) {
      int e = (c << 10) + (t << 2);
      fv4 ka = *reinterpret_cast<const fv4*>(kacc + e);
      fv4 va = *reinterpret_cast<const fv4*>(vacc + e);
      #pragma unroll
      for (int r = 1; r < 4; ++r) {
        ka += *reinterpret_cast<const fv4*>(kacc + (r << 12) + e);
        va += *reinterpret_cast<const fv4*>(vacc + (r << 12) + e);
      }
      k4[c] = ka + *reinterpret_cast<const fv4*>(bk + e);
      v4[c] = va + *reinterpret_cast<const fv4*>(bv + e);
    }
  }
}

template<int NSLOTS, bool PARTIAL>
__global__ __launch_bounds__(256) void kvpass(const float* __restrict__ kin,
    const float* __restrict__ vin,
    const float* __restrict__ bq, const float* __restrict__ bk,
    const float* __restrict__ bv,
    const float* __restrict__ qacc, const float* __restrict__ kacc,
    const float* __restrict__ vacc,
    float* __restrict__ kout, float* __restrict__ vout,
    float* __restrict__ nump, float* __restrict__ denp) {
  __shared__ float wlds[NSLOTS * 32];
  __shared__ int flags[NSLOTS];
  int t = threadIdx.x;
  if (t < NSLOTS) flags[t] = 0;
  // q in registers: sum of 4 replicas + bias
  fv4 q4[4];
  #pragma unroll
  for (int c = 0; c < 4; ++c) {
    int e = (c << 10) + (t << 2);
    fv4 qa = *reinterpret_cast<const fv4*>(qacc + e);
    #pragma unroll
    for (int r = 1; r < 4; ++r)
      qa += *reinterpret_cast<const fv4*>(qacc + (r << 12) + e);
    q4[c] = qa + *reinterpret_cast<const fv4*>(bq + e);
  }
  __syncthreads();   // flags init visible

  float accx[4] = {0,0,0,0}, accy[4] = {0,0,0,0};
  float accz[4] = {0,0,0,0}, accw[4] = {0,0,0,0};
  int base = blockIdx.x * NSLOTS;

  fv4 kc[4], vc[4], kn[4], vn[4];
  load_slot(base, t, kin, vin, kacc, vacc, bk, bv, kc, vc);

  for (int s = 0; s < NSLOTS; ++s) {
    int o = base + s;
    if (s + 1 < NSLOTS)
      load_slot(o + 1, t, kin, vin, kacc, vacc, bk, bv, kn, vn);
    float* kd = kout + (size_t)o * E;
    float* vd = vout + (size_t)o * E;
    #pragma unroll
    for (int c = 0; c < 4; ++c) {
      int e = (c << 10) + (t << 2);
      ntstore4(kd + e, kc[c]);
      ntstore4(vd + e, vc[c]);
    }
    bool nz = false;
    #pragma unroll
    for (int c = 0; c < 4; ++c) {
      float pp = kc[c].x * q4[c].x + kc[c].y * q4[c].y +
                 kc[c].z * q4[c].z + kc[c].w * q4[c].w;
      #pragma unroll
      for (int off = 16; off >= 1; off >>= 1)
        pp += __shfl_xor(pp, off);   // head h = c*8 + (t>>5), dot over 32 lanes
      float w = __expf(pp * SCALE);
      accx[c] += w * vc[c].x; accy[c] += w * vc[c].y;
      accz[c] += w * vc[c].z; accw[c] += w * vc[c].w;
      if ((t & 31) == 0) wlds[(s << 5) + (c << 3) + (t >> 5)] = w;
      nz = nz || vc[c].x != 0.f || vc[c].y != 0.f || vc[c].z != 0.f || vc[c].w != 0.f;
    }
    unsigned long long b = __ballot(nz);
    if ((t & 63) == 0 && b != 0ULL) atomicOr(&flags[s], 1);
    #pragma unroll
    for (int c = 0; c < 4; ++c) { kc[c] = kn[c]; vc[c] = vn[c]; }
  }
  if (PARTIAL) {
    float* np = nump + ((size_t)blockIdx.x << 12);
    #pragma unroll
    for (int c = 0; c < 4; ++c) {
      int e = (c << 10) + (t << 2);
      fv4 val = {accx[c], accy[c], accz[c], accw[c]};
      *reinterpret_cast<fv4*>(np + e) = val;
    }
  } else {
    float* np = nump + ((size_t)(blockIdx.x & 15) << 12);
    #pragma unroll
    for (int c = 0; c < 4; ++c) {
      int e = (c << 10) + (t << 2);
      atomicAdd(np + e + 0, accx[c]);
      atomicAdd(np + e + 1, accy[c]);
      atomicAdd(np + e + 2, accz[c]);
      atomicAdd(np + e + 3, accw[c]);
    }
  }
  __syncthreads();   // wlds + flags complete
  if (t < 32) {
    float d = 0.f;
    #pragma unroll
    for (int s = 0; s < NSLOTS; ++s)
      if (flags[s]) d += wlds[(s << 5) + t];
    if (PARTIAL) denp[blockIdx.x * 64 + t] = d;
    else atomicAdd(denp + (blockIdx.x & 15) * 64 + t, d);
  }
}

// ---------------- K3: sum the NP partials -----------------------------------
template<int NP>
__global__ __launch_bounds__(256) void merge(const float* __restrict__ nump,
    const float* __restrict__ denp, float* __restrict__ num,
    float* __restrict__ den) {
  int b = blockIdx.x;            // 17 blocks: 16 for num, 1 for den
  int t = threadIdx.x;
  if (b < 16) {
    int e = b * 256 + t;
    float s = 0.f;
    #pragma unroll 8
    for (int p = 0; p < NP; ++p) s += nump[((size_t)p << 12) + e];
    num[e] = s;
  } else {
    __shared__ float dl[8][32];
    int g = t >> 5, h = t & 31;
    float d = 0.f;
    for (int p = g; p < NP; p += 8) d += denp[p * 64 + h];
    dl[g][h] = d;
    __syncthreads();
    if (t < 32) {
      float s = 0.f;
      #pragma unroll
      for (int g2 = 0; g2 < 8; ++g2) s += dl[g2][t];
      den[t] = s;
    }
  }
}

// ---------------- K4: output GEMV (values = num/den; exclusive partials) ----
__global__ __launch_bounds__(256) void gemv_out(const float* __restrict__ Wo,
    const float* __restrict__ bo, const float* __restrict__ num,
    const float* __restrict__ den, float* __restrict__ opart) {
  int b = blockIdx.x;            // 256 blocks: 64 i-chunks x 4 col-groups
  int chunk = b >> 2;
  int g = b & 3;
  int t = threadIdx.x;
  int j = (g << 10) + (t << 2);
  __shared__ float vals[64];
  int i0 = chunk << 6;
  if (t < 64) vals[t] = num[i0 + t] / den[(i0 + t) >> 7];
  __syncthreads();
  float ax = 0.f, ay = 0.f, az = 0.f, aw = 0.f;
  #pragma unroll 4
  for (int r = 0; r < 64; ++r) {
    int i = i0 + r;
    float vi = vals[r];
    const fv4 w4 = ntload4(Wo + (size_t)i * E + j);
    ax += vi * w4.x; ay += vi * w4.y; az += vi * w4.z; aw += vi * w4.w;
  }
  if (chunk == 0) {
    const fv4 b4 = *reinterpret_cast<const fv4*>(bo + j);
    ax += b4.x; ay += b4.y; az += b4.z; aw += b4.w;
  }
  fv4 val = {ax, ay, az, aw};
  *reinterpret_cast<fv4*>(opart + (chunk << 12) + j) = val;
}

// ---------------- K5: final out_i = sum of 64 chunk partials ----------------
__global__ __launch_bounds__(256) void writeout(const float* __restrict__ opart,
                                                float* __restrict__ out) {
  int i = blockIdx.x * 256 + threadIdx.x;
  float s = 0.f;
  #pragma unroll 8
  for (int c = 0; c < 64; ++c) s += opart[(c << 12) + i];
  out[i] = s;
}

extern "C" void kernel_launch(void* const* d_in, const int* in_sizes, int n_in,
                              void* d_out, int out_size, void* d_ws, size_t ws_size,
                              hipStream_t stream) {
  const float* x   = (const float*)d_in[0];
  const float* vin = (const float*)d_in[1];
  const float* kin = (const float*)d_in[2];
  const float* Wv  = (const float*)d_in[3];
  const float* bv  = (const float*)d_in[4];
  const float* Wq  = (const float*)d_in[5];
  const float* bq  = (const float*)d_in[6];
  const float* Wk  = (const float*)d_in[7];
  const float* bk  = (const float*)d_in[8];
  const float* Wo  = (const float*)d_in[9];
  const float* bo  = (const float*)d_in[10];
  float* out  = (float*)d_out;
  float* vout = out + E;
  float* kout = vout + (size_t)L * E;
  float* ws   = (float*)d_ws;

  float* qacc = ws;
  float* kacc = ws + 16384;
  float* vacc = ws + 32768;
  const size_t bigFloats = 49152 + (size_t)1024 * 4096 + 1024 * 64 + 4096 + 64 + 64 * 4096;
  bool big = ws_size >= bigFloats * sizeof(float);

  float *nump, *denp, *num, *den, *opart;
  int zcount;
  if (big) {
    nump = ws + 49152;
    denp = nump + (size_t)1024 * 4096;
    num  = denp + 1024 * 64;
    den  = num + 4096;
    opart = den + 64;
    zcount = 49152;                    // only q/k/v accs need zeroing
  } else {
    nump = ws + 49152;
    denp = nump + 16 * 4096;
    num  = denp + 16 * 64;
    den  = num + 4096;
    opart = den + 64;
    zcount = 49152 + 16 * 4096 + 16 * 64;
  }

  zero_ws<<<(zcount + 255) / 256, 256, 0, stream>>>(ws, zcount);
  gemv_qkv<<<384, 256, 0, stream>>>(x, Wq, Wk, Wv, qacc, kacc, vacc);
  if (big) {
    kvpass<8, true><<<L / 8, 256, 0, stream>>>(kin, vin, bq, bk, bv,
        qacc, kacc, vacc, kout, vout, nump, denp);
    merge<1024><<<17, 256, 0, stream>>>(nump, denp, num, den);
  } else {
    kvpass<16, false><<<L / 16, 256, 0, stream>>>(kin, vin, bq, bk, bv,
        qacc, kacc, vacc, kout, vout, nump, denp);
    merge<16><<<17, 256, 0, stream>>>(nump, denp, num, den);
  }
  gemv_out<<<256, 256, 0, stream>>>(Wo, bo, num, den, opart);
  writeout<<<16, 256, 0, stream>>>(opart, out);
}

// Round 8
// 191.847 us; speedup vs baseline: 1.2108x; 1.2108x over previous
//
#include <hip/hip_runtime.h>

#define E 4096
#define H 32
#define L 8192
#define SCALE 0.08838834764831845f  // 1/sqrt(128)

typedef float fv4 __attribute__((ext_vector_type(4)));

__device__ __forceinline__ fv4 ntload4(const float* p) {
  return __builtin_nontemporal_load(reinterpret_cast<const fv4*>(p));
}
__device__ __forceinline__ void ntstore4(float* p, fv4 v) {
  __builtin_nontemporal_store(v, reinterpret_cast<fv4*>(p));
}

// ---------------- K0: zero the q/k/v accumulator region ---------------------
__global__ __launch_bounds__(256) void zero_ws(float* __restrict__ ws, int n) {
  int i = blockIdx.x * 256 + threadIdx.x;
  if (i < n) ws[i] = 0.f;
}

// ---------------- K1: fused q/k/v GEMV (split-K, 4-rep atomic partials) -----
__global__ __launch_bounds__(256) void gemv_qkv(const float* __restrict__ x,
    const float* __restrict__ Wq, const float* __restrict__ Wk,
    const float* __restrict__ Wv, float* __restrict__ qacc,
    float* __restrict__ kacc, float* __restrict__ vacc) {
  int b = blockIdx.x;            // 384 blocks: 3 mats x 32 chunks x 4 col-groups
  int mat = b >> 7;
  int rem = b & 127;
  int chunk = rem >> 2;          // 32 chunks of 128 rows
  int g = rem & 3;               // 4 col groups of 1024
  const float* W = (mat == 0) ? Wq : (mat == 1) ? Wk : Wv;
  float* accb = (mat == 0) ? qacc : (mat == 1) ? kacc : vacc;
  int rep = (b >> 2) & 3;
  float* acc = accb + (rep << 12);
  int t = threadIdx.x;
  int j = (g << 10) + (t << 2);
  float ax = 0.f, ay = 0.f, az = 0.f, aw = 0.f;
  int i0 = chunk << 7;
  #pragma unroll 8
  for (int r = 0; r < 128; ++r) {
    int i = i0 + r;
    float xi = x[i];
    const fv4 w4 = ntload4(W + (size_t)i * E + j);
    ax += xi * w4.x; ay += xi * w4.y; az += xi * w4.z; aw += xi * w4.w;
  }
  atomicAdd(acc + j + 0, ax);
  atomicAdd(acc + j + 1, ay);
  atomicAdd(acc + j + 2, az);
  atomicAdd(acc + j + 3, aw);
}

// ---------------- K2: fused k+v shift + logits + accumulation ---------------
// PARTIAL=true : per-block exclusive partial stores (no RMW, no contention).
// PARTIAL=false: 16-replica atomics (fallback for small ws).
__device__ __forceinline__ void load_slot(int o, int t,
    const float* __restrict__ kin, const float* __restrict__ vin,
    const float* __restrict__ kacc, const float* __restrict__ vacc,
    const float* __restrict__ bk, const float* __restrict__ bv,
    fv4 k4[4], fv4 v4[4]) {
  if (o < L - 1) {
    const float* ks = kin + (size_t)(o + 1) * E;
    const float* vs = vin + (size_t)(o + 1) * E;
    #pragma unroll
    for (int c = 0; c < 4; ++c) {
      int e = (c << 10) + (t << 2);
      k4[c] = ntload4(ks + e);
      v4[c] = ntload4(vs + e);
    }
  } else {
    #pragma unroll
    for (int c = 0; c < 4; ++c) {
      int e = (c << 10) + (t << 2);
      fv4 ka = *reinterpret_cast<const fv4*>(kacc + e);
      fv4 va = *reinterpret_cast<const fv4*>(vacc + e);
      #pragma unroll
      for (int r = 1; r < 4; ++r) {
        ka += *reinterpret_cast<const fv4*>(kacc + (r << 12) + e);
        va += *reinterpret_cast<const fv4*>(vacc + (r << 12) + e);
      }
      k4[c] = ka + *reinterpret_cast<const fv4*>(bk + e);
      v4[c] = va + *reinterpret_cast<const fv4*>(bv + e);
    }
  }
}

template<int NSLOTS, bool PARTIAL>
__global__ __launch_bounds__(256) void kvpass(const float* __restrict__ kin,
    const float* __restrict__ vin,
    const float* __restrict__ bq, const float* __restrict__ bk,
    const float* __restrict__ bv,
    const float* __restrict__ qacc, const float* __restrict__ kacc,
    const float* __restrict__ vacc,
    float* __restrict__ kout, float* __restrict__ vout,
    float* __restrict__ nump, float* __restrict__ denp) {
  __shared__ float wlds[NSLOTS * 32];
  __shared__ int flags[NSLOTS];
  int t = threadIdx.x;
  for (int s = t; s < NSLOTS; s += 256) flags[s] = 0;
  // q in registers: sum of 4 replicas + bias
  fv4 q4[4];
  #pragma unroll
  for (int c = 0; c < 4; ++c) {
    int e = (c << 10) + (t << 2);
    fv4 qa = *reinterpret_cast<const fv4*>(qacc + e);
    #pragma unroll
    for (int r = 1; r < 4; ++r)
      qa += *reinterpret_cast<const fv4*>(qacc + (r << 12) + e);
    q4[c] = qa + *reinterpret_cast<const fv4*>(bq + e);
  }
  __syncthreads();   // flags init visible

  float accx[4] = {0,0,0,0}, accy[4] = {0,0,0,0};
  float accz[4] = {0,0,0,0}, accw[4] = {0,0,0,0};
  int base = blockIdx.x * NSLOTS;

  fv4 kc[4], vc[4], kn[4], vn[4];
  load_slot(base, t, kin, vin, kacc, vacc, bk, bv, kc, vc);

  for (int s = 0; s < NSLOTS; ++s) {
    int o = base + s;
    if (s + 1 < NSLOTS)
      load_slot(o + 1, t, kin, vin, kacc, vacc, bk, bv, kn, vn);
    float* kd = kout + (size_t)o * E;
    float* vd = vout + (size_t)o * E;
    #pragma unroll
    for (int c = 0; c < 4; ++c) {
      int e = (c << 10) + (t << 2);
      ntstore4(kd + e, kc[c]);
      ntstore4(vd + e, vc[c]);
    }
    bool nz = false;
    #pragma unroll
    for (int c = 0; c < 4; ++c) {
      float pp = kc[c].x * q4[c].x + kc[c].y * q4[c].y +
                 kc[c].z * q4[c].z + kc[c].w * q4[c].w;
      #pragma unroll
      for (int off = 16; off >= 1; off >>= 1)
        pp += __shfl_xor(pp, off);   // head h = c*8 + (t>>5), dot over 32 lanes
      float w = __expf(pp * SCALE);
      accx[c] += w * vc[c].x; accy[c] += w * vc[c].y;
      accz[c] += w * vc[c].z; accw[c] += w * vc[c].w;
      if ((t & 31) == 0) wlds[(s << 5) + (c << 3) + (t >> 5)] = w;
      nz = nz || vc[c].x != 0.f || vc[c].y != 0.f || vc[c].z != 0.f || vc[c].w != 0.f;
    }
    unsigned long long b = __ballot(nz);
    if ((t & 63) == 0 && b != 0ULL) atomicOr(&flags[s], 1);
    #pragma unroll
    for (int c = 0; c < 4; ++c) { kc[c] = kn[c]; vc[c] = vn[c]; }
  }
  if (PARTIAL) {
    float* np = nump + ((size_t)blockIdx.x << 12);
    #pragma unroll
    for (int c = 0; c < 4; ++c) {
      int e = (c << 10) + (t << 2);
      fv4 val = {accx[c], accy[c], accz[c], accw[c]};
      *reinterpret_cast<fv4*>(np + e) = val;
    }
  } else {
    float* np = nump + ((size_t)(blockIdx.x & 15) << 12);
    #pragma unroll
    for (int c = 0; c < 4; ++c) {
      int e = (c << 10) + (t << 2);
      atomicAdd(np + e + 0, accx[c]);
      atomicAdd(np + e + 1, accy[c]);
      atomicAdd(np + e + 2, accz[c]);
      atomicAdd(np + e + 3, accw[c]);
    }
  }
  __syncthreads();   // wlds + flags complete
  if (t < 32) {
    float d = 0.f;
    #pragma unroll
    for (int s = 0; s < NSLOTS; ++s)
      if (flags[s]) d += wlds[(s << 5) + t];
    if (PARTIAL) denp[blockIdx.x * 64 + t] = d;
    else atomicAdd(denp + (blockIdx.x & 15) * 64 + t, d);
  }
}

// ---------------- K3: sum the NP partials -----------------------------------
template<int NP>
__global__ __launch_bounds__(256) void merge(const float* __restrict__ nump,
    const float* __restrict__ denp, float* __restrict__ num,
    float* __restrict__ den) {
  int b = blockIdx.x;            // 17 blocks: 16 for num, 1 for den
  int t = threadIdx.x;
  if (b < 16) {
    int e = b * 256 + t;
    float s = 0.f;
    #pragma unroll 8
    for (int p = 0; p < NP; ++p) s += nump[((size_t)p << 12) + e];
    num[e] = s;
  } else {
    __shared__ float dl[8][32];
    int g = t >> 5, h = t & 31;
    float d = 0.f;
    for (int p = g; p < NP; p += 8) d += denp[p * 64 + h];
    dl[g][h] = d;
    __syncthreads();
    if (t < 32) {
      float s = 0.f;
      #pragma unroll
      for (int g2 = 0; g2 < 8; ++g2) s += dl[g2][t];
      den[t] = s;
    }
  }
}

// ---------------- K4: output GEMV (values = num/den; exclusive partials) ----
__global__ __launch_bounds__(256) void gemv_out(const float* __restrict__ Wo,
    const float* __restrict__ bo, const float* __restrict__ num,
    const float* __restrict__ den, float* __restrict__ opart) {
  int b = blockIdx.x;            // 256 blocks: 64 i-chunks x 4 col-groups
  int chunk = b >> 2;
  int g = b & 3;
  int t = threadIdx.x;
  int j = (g << 10) + (t << 2);
  __shared__ float vals[64];
  int i0 = chunk << 6;
  if (t < 64) vals[t] = num[i0 + t] / den[(i0 + t) >> 7];
  __syncthreads();
  float ax = 0.f, ay = 0.f, az = 0.f, aw = 0.f;
  #pragma unroll 4
  for (int r = 0; r < 64; ++r) {
    int i = i0 + r;
    float vi = vals[r];
    const fv4 w4 = ntload4(Wo + (size_t)i * E + j);
    ax += vi * w4.x; ay += vi * w4.y; az += vi * w4.z; aw += vi * w4.w;
  }
  if (chunk == 0) {
    const fv4 b4 = *reinterpret_cast<const fv4*>(bo + j);
    ax += b4.x; ay += b4.y; az += b4.z; aw += b4.w;
  }
  fv4 val = {ax, ay, az, aw};
  *reinterpret_cast<fv4*>(opart + (chunk << 12) + j) = val;
}

// ---------------- K5: final out_i = sum of 64 chunk partials ----------------
__global__ __launch_bounds__(256) void writeout(const float* __restrict__ opart,
                                                float* __restrict__ out) {
  int i = blockIdx.x * 256 + threadIdx.x;
  float s = 0.f;
  #pragma unroll 8
  for (int c = 0; c < 64; ++c) s += opart[(c << 12) + i];
  out[i] = s;
}

extern "C" void kernel_launch(void* const* d_in, const int* in_sizes, int n_in,
                              void* d_out, int out_size, void* d_ws, size_t ws_size,
                              hipStream_t stream) {
  const float* x   = (const float*)d_in[0];
  const float* vin = (const float*)d_in[1];
  const float* kin = (const float*)d_in[2];
  const float* Wv  = (const float*)d_in[3];
  const float* bv  = (const float*)d_in[4];
  const float* Wq  = (const float*)d_in[5];
  const float* bq  = (const float*)d_in[6];
  const float* Wk  = (const float*)d_in[7];
  const float* bk  = (const float*)d_in[8];
  const float* Wo  = (const float*)d_in[9];
  const float* bo  = (const float*)d_in[10];
  float* out  = (float*)d_out;
  float* vout = out + E;
  float* kout = vout + (size_t)L * E;
  float* ws   = (float*)d_ws;

  float* qacc = ws;
  float* kacc = ws + 16384;
  float* vacc = ws + 32768;
  // big layout: 256 exclusive num partials (4 MB) + den partials + finals
  const size_t bigFloats = 49152 + (size_t)256 * 4096 + 256 * 64 + 4096 + 64
                         + (size_t)64 * 4096;
  bool big = ws_size >= bigFloats * sizeof(float);

  float *nump, *denp, *num, *den, *opart;
  int zcount;
  if (big) {
    nump = ws + 49152;
    denp = nump + (size_t)256 * 4096;
    num  = denp + 256 * 64;
    den  = num + 4096;
    opart = den + 64;
    zcount = 49152;                    // only q/k/v accs need zeroing
  } else {
    nump = ws + 49152;
    denp = nump + 16 * 4096;
    num  = denp + 16 * 64;
    den  = num + 4096;
    opart = den + 64;
    zcount = 49152 + 16 * 4096 + 16 * 64;
  }

  zero_ws<<<(zcount + 255) / 256, 256, 0, stream>>>(ws, zcount);
  gemv_qkv<<<384, 256, 0, stream>>>(x, Wq, Wk, Wv, qacc, kacc, vacc);
  if (big) {
    kvpass<32, true><<<L / 32, 256, 0, stream>>>(kin, vin, bq, bk, bv,
        qacc, kacc, vacc, kout, vout, nump, denp);
    merge<256><<<17, 256, 0, stream>>>(nump, denp, num, den);
  } else {
    kvpass<16, false><<<L / 16, 256, 0, stream>>>(kin, vin, bq, bk, bv,
        qacc, kacc, vacc, kout, vout, nump, denp);
    merge<16><<<17, 256, 0, stream>>>(nump, denp, num, den);
  }
  gemv_out<<<256, 256, 0, stream>>>(Wo, bo, num, den, opart);
  writeout<<<16, 256, 0, stream>>>(opart, out);
}